// Round 3
// baseline (279.913 us; speedup 1.0000x reference)
//
#include <hip/hip_runtime.h>
#include <hip/hip_bf16.h>
#include <stdint.h>
#include <stddef.h>

// BiAttentionLayer: B=8, Tc=4096, Tq=1024, D=256, fp32 in/out.
// Math: s_c (w1) cancels in softmax/U/b. exp without running max is safe
// (|S+s_q| <= ~15). b[i] = exp(m)/l.
// Round-3: barrier-free K-loop (all operands direct from L2 in frag order),
// 2-way j-split for 16 waves/CU grid cap, raw-partial combine in k_epilogue
// (which also fuses the h reduction). Partial U parks in d_out as scratch.

#define NB 8
#define TC 4096
#define TQ 1024
#define DD 256
#define JT 32
#define NJT (TQ / JT)

typedef __attribute__((ext_vector_type(4)))  float  f32x4v;
typedef __attribute__((ext_vector_type(8)))  __bf16 bf16x8v;
typedef __attribute__((ext_vector_type(4)))  __bf16 bf16x4v;

// workspace layout (bytes), ~8.6 MB
#define QA_OFF   0                              // bf16 mm1-A frag order [b][it][jm][c][L][8] (4 MiB)
#define QX_OFF   (QA_OFF + NB*NJT*16*1024)      // bf16 mm2-B frag order [b][it][mt][L][8]    (4 MiB)
#define SQ_OFF   (QX_OFF + NB*NJT*16*1024)      // f32 [NB][TQ]
#define PL_OFF   (SQ_OFF + NB*TQ*4)             // f32 [2][NB][TC]  partial l
#define PM_OFF   (PL_OFF + 2*NB*TC*4)           // f32 [2][NB][TC]  partial m
#define HV_OFF   (PM_OFF + 2*NB*TC*4)           // f32 [NB][DD]

// ---------------- kernel 0: question preprocessing ----------------
__global__ __launch_bounds__(256) void k_qprep(const float* __restrict__ question,
                                               const float* __restrict__ w,
                                               char* __restrict__ ws) {
  uint4* qa = (uint4*)(ws + QA_OFF);
  uint4* qx = (uint4*)(ws + QX_OFF);
  float* sq = (float*)(ws + SQ_OFF);
  __shared__ __align__(16) __bf16 T[32][264];

  int bx = blockIdx.x;
  int b = bx >> 5, it = bx & 31;
  int t = threadIdx.x;
  int j = t >> 3;
  int seg = t & 7;

  const float* qrow = question + ((size_t)(b * TQ + it * JT + j)) * DD + seg * 32;
  const float* w2 = w + DD;

  float part = 0.f;
#pragma unroll
  for (int k = 0; k < 8; ++k) {
    float4 v  = *(const float4*)(qrow + 4 * k);
    float4 wv = *(const float4*)(w2 + seg * 32 + 4 * k);
    part += v.x * wv.x + v.y * wv.y + v.z * wv.z + v.w * wv.w;
    bf16x4v pk = {(__bf16)v.x, (__bf16)v.y, (__bf16)v.z, (__bf16)v.w};
    *(bf16x4v*)&T[j][seg * 32 + 4 * k] = pk;
  }
  part += __shfl_xor(part, 1);
  part += __shfl_xor(part, 2);
  part += __shfl_xor(part, 4);
  if (seg == 0) sq[b * TQ + it * JT + j] = part;
  __syncthreads();

  // qa: ch = (jm*8+c)*64 + L ; element T[16*jm + (L&15)][32*c + 8*(L>>4) + o]
#pragma unroll
  for (int p = 0; p < 4; ++p) {
    int ch = t + 256 * p;
    int L = ch & 63, cc = ch >> 6;
    int jm = cc >> 3, c = cc & 7;
    int nh = L & 15, qh = L >> 4;
    uint4 v = *(const uint4*)&T[16 * jm + nh][32 * c + 8 * qh];
    qa[(size_t)(b * NJT + it) * 1024 + ch] = v;
  }
  // qx: ch = mt*64 + L ; element T[8*(L>>4) + o][16*mt + (L&15)]
#pragma unroll
  for (int p = 0; p < 4; ++p) {
    int ch = t + 256 * p;
    int L = ch & 63, mt = ch >> 6;
    int nh = L & 15, qh = L >> 4;
    __bf16 e[8];
#pragma unroll
    for (int o = 0; o < 8; ++o) e[o] = T[8 * qh + o][16 * mt + nh];
    qx[(size_t)(b * NJT + it) * 1024 + ch] = *(const uint4*)e;
  }
}

// ---------------- kernel 1: barrier-free partial attention ----------------
// 1024 blocks x 256 thr: bx = (js<<9) | (ig<<3) | b. Wave owns 16 i, 16 j-tiles.
// Partials: U_raw (f32 frags) -> block's own region of d_out; l,m -> ws.
__global__ __launch_bounds__(256, 3) void k_main(const float* __restrict__ context,
                                                 const float* __restrict__ w,
                                                 const char* __restrict__ ws,
                                                 float* __restrict__ out) {
  const uint4*  qa = (const uint4*)(ws + QA_OFF);
  const __bf16* qx = (const __bf16*)(ws + QX_OFF);
  const float*  sq = (const float*)(ws + SQ_OFF);
  float* pl = (float*)((char*)ws + PL_OFF);   // ws is const char*; cast away for stores
  float* pm = (float*)((char*)ws + PM_OFF);

  __shared__ __align__(16) __bf16 pa_lds[4][16][40]; // per-wave P buffer only

  int bx = blockIdx.x;
  int js = bx >> 9;
  int b = bx & 7;                 // XCD-affine
  int ig = (bx >> 3) & 63;
  int t = threadIdx.x;
  int wv = t >> 6;
  int lane = t & 63;
  int nh = lane & 15;
  int qh = lane >> 4;
  int i0w = ig * 64 + wv * 16;

  // cw3 B-frags: B[k=d][n=i] = context[i0w+nh][d]*w3[d], d = 32c + 8qh + o
  bf16x8v cw3f[8];
  {
    const float* crow = context + ((size_t)(b * TC + i0w + nh)) * DD;
    const float* w3 = w + 2 * DD;
#pragma unroll
    for (int c = 0; c < 8; ++c) {
      int d0 = 32 * c + 8 * qh;
      float4 f0 = *(const float4*)(crow + d0);
      float4 f1 = *(const float4*)(crow + d0 + 4);
      float4 g0 = *(const float4*)(w3 + d0);
      float4 g1 = *(const float4*)(w3 + d0 + 4);
      bf16x8v fr;
      fr[0] = (__bf16)(f0.x * g0.x); fr[1] = (__bf16)(f0.y * g0.y);
      fr[2] = (__bf16)(f0.z * g0.z); fr[3] = (__bf16)(f0.w * g0.w);
      fr[4] = (__bf16)(f1.x * g1.x); fr[5] = (__bf16)(f1.y * g1.y);
      fr[6] = (__bf16)(f1.z * g1.z); fr[7] = (__bf16)(f1.w * g1.w);
      cw3f[c] = fr;
    }
  }

  f32x4v U[16];
#pragma unroll
  for (int mt = 0; mt < 16; ++mt) U[mt] = (f32x4v){0.f, 0.f, 0.f, 0.f};
  float m_run = -1e30f, l_run = 0.f;

  const uint4*  qa_b = qa + (size_t)b * NJT * 1024;
  const __bf16* qx_b = qx + (size_t)b * NJT * 8192;
  const float*  sqb = sq + b * TQ;

  for (int k = 0; k < 16; ++k) {
    int itq = js * 16 + k;
    const uint4* qat = qa_b + (size_t)itq * 1024;

    // mm1: S^T[32j][16i], K=256 in 8 chunks, A-frags direct from L2
    f32x4v S0 = {0.f, 0.f, 0.f, 0.f}, S1 = {0.f, 0.f, 0.f, 0.f};
#pragma unroll
    for (int c = 0; c < 8; ++c) {
      bf16x8v a0 = *(const bf16x8v*)&qat[c * 64 + lane];
      bf16x8v a1 = *(const bf16x8v*)&qat[(8 + c) * 64 + lane];
      S0 = __builtin_amdgcn_mfma_f32_16x16x32_bf16(a0, cw3f[c], S0, 0, 0, 0);
      S1 = __builtin_amdgcn_mfma_f32_16x16x32_bf16(a1, cw3f[c], S1, 0, 0, 0);
    }

    // P = exp(S + s_q); lazy m; running l
    float4 sq0 = *(const float4*)(sqb + itq * JT + 4 * qh);
    float4 sq1 = *(const float4*)(sqb + itq * JT + 16 + 4 * qh);
    float v0 = S0[0] + sq0.x, v1 = S0[1] + sq0.y, v2 = S0[2] + sq0.z, v3 = S0[3] + sq0.w;
    float u0 = S1[0] + sq1.x, u1 = S1[1] + sq1.y, u2 = S1[2] + sq1.z, u3 = S1[3] + sq1.w;
    m_run = fmaxf(m_run, fmaxf(fmaxf(fmaxf(v0, v1), fmaxf(v2, v3)),
                               fmaxf(fmaxf(u0, u1), fmaxf(u2, u3))));
    float e0 = __expf(v0), e1 = __expf(v1), e2 = __expf(v2), e3 = __expf(v3);
    float f0 = __expf(u0), f1 = __expf(u1), f2 = __expf(u2), f3 = __expf(u3);
    l_run += ((e0 + e1) + (e2 + e3)) + ((f0 + f1) + (f2 + f3));

    // per-wave LDS round trip: C layout -> A-operand layout (wave-synchronous)
    bf16x4v pk0 = {(__bf16)e0, (__bf16)e1, (__bf16)e2, (__bf16)e3};
    bf16x4v pk1 = {(__bf16)f0, (__bf16)f1, (__bf16)f2, (__bf16)f3};
    *(bf16x4v*)&pa_lds[wv][nh][4 * qh]      = pk0;
    *(bf16x4v*)&pa_lds[wv][nh][16 + 4 * qh] = pk1;
    bf16x8v af = *(const bf16x8v*)&pa_lds[wv][nh][8 * qh];

    // mm2: U[16i][16d] per mt, K=32, B-frags direct from L2
    const __bf16* qxt = qx_b + (size_t)itq * 8192 + lane * 8;
#pragma unroll
    for (int mt = 0; mt < 16; ++mt) {
      bf16x8v bq = *(const bf16x8v*)(qxt + mt * 512);
      U[mt] = __builtin_amdgcn_mfma_f32_16x16x32_bf16(af, bq, U[mt], 0, 0, 0);
    }
  }

  // reduce l, m across quads; lanes 0..15 own i = i0w + nh
  float lo = l_run + __shfl_xor(l_run, 16);
  lo += __shfl_xor(lo, 32);
  float mo = fmaxf(m_run, __shfl_xor(m_run, 16));
  mo = fmaxf(mo, __shfl_xor(mo, 32));
  if (lane < 16) {
    pl[(js * 8 + b) * TC + i0w + nh] = lo;
    pm[(js * 8 + b) * TC + i0w + nh] = mo;
  }

  // partial U (f32 frags) into this block's own G region (scratch)
  float* sb = out + ((size_t)(b * TC + ig * 64)) * 1024;
#pragma unroll
  for (int mt = 0; mt < 16; ++mt) {
    *(f32x4v*)(sb + (((js * 4 + wv) * 16 + mt) * 256 + lane * 4)) = U[mt];
  }
}

// ---------------- kernel 2: combine partials, write G0/1/2, h-partials ----------------
__global__ __launch_bounds__(256) void k_epilogue(const float* __restrict__ context,
                                                  const char* __restrict__ ws,
                                                  float* __restrict__ out,
                                                  float* __restrict__ hv) {
  const float* pl = (const float*)(ws + PL_OFF);
  const float* pm = (const float*)(ws + PM_OFF);
  __shared__ float hblk[4][256];

  int bx = blockIdx.x;
  int b = bx & 7;
  int ig = bx >> 3;
  int t = threadIdx.x;
  int wv = t >> 6;
  int lane = t & 63;
  int nh = lane & 15;
  int qh = lane >> 4;
  int i0w = ig * 64 + wv * 16;

  float* sb = out + ((size_t)(b * TC + ig * 64)) * 1024;

  // read both splits' partial frags (must finish before any G write)
  f32x4v U[16];
#pragma unroll
  for (int mt = 0; mt < 16; ++mt) {
    f32x4v a = *(const f32x4v*)(sb + (((0 * 4 + wv) * 16 + mt) * 256 + lane * 4));
    f32x4v c = *(const f32x4v*)(sb + (((1 * 4 + wv) * 16 + mt) * 256 + lane * 4));
    U[mt] = a + c;
  }
  int i = i0w + nh;
  float l0 = pl[(0 * 8 + b) * TC + i], l1 = pl[(1 * 8 + b) * TC + i];
  float m0 = pm[(0 * 8 + b) * TC + i], m1 = pm[(1 * 8 + b) * TC + i];
  float rinv = 1.0f / (l0 + l1);
  float bval = __expf(fmaxf(m0, m1)) * rinv;
  __syncthreads();   // partial reads complete before overwriting region

  float rv[4], bw[4];
#pragma unroll
  for (int r = 0; r < 4; ++r) {
    rv[r] = __shfl(rinv, 4 * qh + r);
    bw[r] = __shfl(bval, 4 * qh + r);
  }

  float hacc[16];
#pragma unroll
  for (int mt = 0; mt < 16; ++mt) hacc[mt] = 0.f;

#pragma unroll
  for (int r = 0; r < 4; ++r) {
    int row = i0w + 4 * qh + r;
    const float* crow = context + ((size_t)(b * TC + row)) * DD;
    float* orow = out + ((size_t)(b * TC + row)) * (4 * DD);
#pragma unroll
    for (int mt = 0; mt < 16; ++mt) {
      int d = 16 * mt + nh;
      float c = crow[d];
      float u = U[mt][r] * rv[r];
      orow[d] = c;
      orow[DD + d] = u;
      orow[2 * DD + d] = c * u;
      hacc[mt] += bw[r] * c;
    }
  }

  // h-partial: sum across quads -> qh==0 lanes hold sum over this wave's 16 i
#pragma unroll
  for (int mt = 0; mt < 16; ++mt) {
    hacc[mt] += __shfl_xor(hacc[mt], 16);
    hacc[mt] += __shfl_xor(hacc[mt], 32);
  }
  if (qh == 0) {
#pragma unroll
    for (int mt = 0; mt < 16; ++mt) hblk[wv][16 * mt + nh] = hacc[mt];
  }
  __syncthreads();
  if (t < 256) {
    float hsum = hblk[0][t] + hblk[1][t] + hblk[2][t] + hblk[3][t];
    atomicAdd(&hv[b * DD + t], hsum);
  }
}

// ---------------- kernel 3: G chunk 3 = context * H ----------------
__global__ __launch_bounds__(256) void k_final(const float* __restrict__ context,
                                               const char* __restrict__ ws,
                                               float* __restrict__ out) {
  const float* hv = (const float*)(ws + HV_OFF);
  int gid = blockIdx.x * 256 + threadIdx.x;
  int row = gid >> 6;
  int d = (gid & 63) * 4;
  int b = row >> 12;
  float4 c4 = ((const float4*)context)[gid];
  float4 h4 = *(const float4*)(hv + b * DD + d);
  float4 r;
  r.x = c4.x * h4.x; r.y = c4.y * h4.y; r.z = c4.z * h4.z; r.w = c4.w * h4.w;
  *(float4*)(out + (size_t)row * TQ + 3 * DD + d) = r;
}

extern "C" void kernel_launch(void* const* d_in, const int* in_sizes, int n_in,
                              void* d_out, int out_size, void* d_ws, size_t ws_size,
                              hipStream_t stream) {
  (void)in_sizes; (void)n_in; (void)out_size; (void)ws_size;
  const float* context  = (const float*)d_in[0];
  const float* question = (const float*)d_in[1];
  const float* w        = (const float*)d_in[2];
  float* out = (float*)d_out;
  char* ws = (char*)d_ws;

  k_qprep<<<NB * NJT, 256, 0, stream>>>(question, w, ws);
  k_main<<<2 * NB * (TC / 64), 256, 0, stream>>>(context, w, ws, out);
  hipMemsetAsync(ws + HV_OFF, 0, NB * DD * sizeof(float), stream);
  k_epilogue<<<NB * (TC / 64), 256, 0, stream>>>(context, ws, out,
                                                 (float*)(ws + HV_OFF));
  k_final<<<(NB * TC * DD / 4) / 256, 256, 0, stream>>>(context, ws, out);
}